// Round 4
// baseline (118.415 us; speedup 1.0000x reference)
//
#include <hip/hip_runtime.h>
#include <hip/hip_bf16.h>

// BatchIrregularDownsample2d (D=2): out[b,c,j] = in[b,c,G[b,j]]
// R4: 4 quads per thread with batched load issue (deep MLP). Phases:
//   A) compute addresses, issue prefix loads + tail index loads (independent)
//   B) issue tail gather loads (4-deep pipelined)
//   C) slow quads (row/region boundaries)
//   D) 4 aligned float4 stores

#define HW_FULL 65536
#define T1     1024
#define PER_T  16

typedef float f4a __attribute__((ext_vector_type(4), aligned(4)));
typedef int   i4a __attribute__((ext_vector_type(4), aligned(4)));

__global__ __launch_bounds__(1024) void build_idx_kernel(
    const int* __restrict__ mask, int* __restrict__ hdr, int* __restrict__ gt, int M)
{
    const int b = blockIdx.x;
    const int t = threadIdx.x;
    const int* mb = mask + (long long)b * HW_FULL;

    unsigned char fl[PER_T];
    unsigned long long local = 0ULL;
    #pragma unroll
    for (int k = 0; k < PER_T; ++k) {
        int e = t * PER_T + k;
        int r = e >> 7;
        int c = e & 127;
        int m = mb[(r << 9) + (c << 1)];
        int z  = (m == 0);
        int cs = (m >= 1);
        int dt = (m == 1);
        int tl = ((r | c) & 1) == 0;
        int kl = (tl && (m >= 2)) ? 1 : 0;
        fl[k] = (unsigned char)(z | (cs << 1) | (dt << 2) | (kl << 3));
        local += (unsigned long long)z
               | ((unsigned long long)cs << 16)
               | ((unsigned long long)dt << 32)
               | ((unsigned long long)kl << 48);
    }

    __shared__ unsigned long long sh[T1];
    sh[t] = local;
    __syncthreads();
    for (int off = 1; off < T1; off <<= 1) {
        unsigned long long v = (t >= off) ? sh[t - off] : 0ULL;
        __syncthreads();
        sh[t] += v;
        __syncthreads();
    }
    unsigned long long tot = sh[T1 - 1];
    unsigned long long ex  = (t > 0) ? sh[t - 1] : 0ULL;

    const int zt    = (int)( tot        & 0xFFFF);
    const int ndt   = (int)((tot >> 32) & 0xFFFF);
    const int nkl   = (int)((tot >> 48) & 0xFFFF);
    const int start = zt * 4;

    int csP = (int)((ex >> 16) & 0xFFFF);
    int dtP = (int)((ex >> 32) & 0xFFFF);
    int klP = (int)((ex >> 48) & 0xFFFF);

    int* gtb = gt + (long long)b * M;
    #pragma unroll
    for (int k = 0; k < PER_T; ++k) {
        int f = fl[k];
        if (f & 4) { gtb[dtP]       = start + csP; ++dtP; }
        if (f & 8) { gtb[ndt + klP] = start + csP; ++klP; }
        if (f & 2) { ++csP; }
    }

    if (t == 0) {
        hdr[b * 4 + 0] = start;
        hdr[b * 4 + 1] = ndt;
        hdr[b * 4 + 2] = nkl;
        hdr[b * 4 + 3] = start + ndt + nkl;
    }
}

#define KQ 4          // quads per thread
#define CAT_NONE 0
#define CAT_PRE  1
#define CAT_TAIL 2
#define CAT_SLOW 3

__global__ __launch_bounds__(256) void gather4x4_kernel(
    const float* __restrict__ in,
    const int* __restrict__ hdr,
    const int* __restrict__ gt,
    float* __restrict__ out,
    int N, int M, int cshift,
    unsigned long long total,
    unsigned long long magic, int rshift)
{
    const int tid = threadIdx.x;
    const unsigned long long qbase =
        (unsigned long long)blockIdx.x * (256ULL * KQ) + (unsigned)tid;

    int cat[KQ];
    unsigned long long oo[KQ];
    const float* rin[KQ];
    float4 v[KQ];
    i4a idxv[KQ];

    // Phase A: addresses + issue independent first-hop loads
    #pragma unroll
    for (int k = 0; k < KQ; ++k) {
        unsigned long long o = (qbase + (unsigned long long)k * 256ULL) << 2;
        oo[k] = o;
        cat[k] = CAT_NONE;
        rin[k] = in;
        if (o < total) {
            unsigned int row = (unsigned int)((o * magic) >> rshift);
            int j = (int)(o - (unsigned long long)row * (unsigned)M);
            int b = row >> cshift;
            const float* rp = in + (unsigned long long)row * (unsigned)N;
            rin[k] = rp;
            if (j + 3 < M) {
                int start = hdr[b * 4 + 0];
                int len   = hdr[b * 4 + 3];
                if (j + 3 < start) {
                    cat[k] = CAT_PRE;
                    f4a lv = *reinterpret_cast<const f4a*>(rp + j);
                    v[k] = make_float4(lv.x, lv.y, lv.z, lv.w);
                } else if (j >= start && j + 3 < len) {
                    cat[k] = CAT_TAIL;
                    const int* gtb = gt + (unsigned long long)b * (unsigned)M;
                    idxv[k] = *reinterpret_cast<const i4a*>(gtb + (j - start));
                } else {
                    cat[k] = CAT_SLOW;
                }
            } else {
                cat[k] = CAT_SLOW;
            }
        }
    }

    // Phase B: second-hop gather loads (pipelined across k)
    #pragma unroll
    for (int k = 0; k < KQ; ++k) {
        if (cat[k] == CAT_TAIL) {
            const float* rp = rin[k];
            v[k] = make_float4(rp[idxv[k].x], rp[idxv[k].y],
                               rp[idxv[k].z], rp[idxv[k].w]);
        }
    }

    // Phase C: slow quads (row/region boundary)
    #pragma unroll
    for (int k = 0; k < KQ; ++k) {
        if (cat[k] == CAT_SLOW) {
            float* vf = reinterpret_cast<float*>(&v[k]);
            #pragma unroll
            for (int e = 0; e < 4; ++e) {
                unsigned long long ok = oo[k] + e;
                float x = 0.0f;
                if (ok < total) {
                    unsigned int r2 = (unsigned int)((ok * magic) >> rshift);
                    int j2 = (int)(ok - (unsigned long long)r2 * (unsigned)M);
                    int b2 = r2 >> cshift;
                    int s2 = hdr[b2 * 4 + 0];
                    int l2 = hdr[b2 * 4 + 3];
                    if (j2 < l2) {
                        int src = (j2 < s2) ? j2
                                : gt[(unsigned long long)b2 * (unsigned)M + (j2 - s2)];
                        x = in[(unsigned long long)r2 * (unsigned)N + src];
                    }
                }
                vf[e] = x;
            }
        }
    }

    // Phase D: aligned float4 stores
    #pragma unroll
    for (int k = 0; k < KQ; ++k) {
        if (cat[k] != CAT_NONE) {
            *reinterpret_cast<float4*>(out + oo[k]) = v[k];
        }
    }
}

extern "C" void kernel_launch(void* const* d_in, const int* in_sizes, int n_in,
                              void* d_out, int out_size, void* d_ws, size_t ws_size,
                              hipStream_t stream) {
    const float* x    = (const float*)d_in[0];
    const int*   mask = (const int*)d_in[1];
    float*       out  = (float*)d_out;

    const int B = in_sizes[1] / HW_FULL;          // 8
    const int C = 256;
    const int N = in_sizes[0] / (B * C);          // 32776
    const int M = out_size   / (B * C);           // 28681

    int cshift = 0;
    while ((1 << cshift) < C) ++cshift;

    int rshift = 40;
    while ((unsigned long long)M * (unsigned long long)out_size >= (1ULL << rshift)) ++rshift;
    unsigned long long magic = ((1ULL << rshift) / (unsigned)M) + 1;

    int* hdr = (int*)d_ws;                        // B*4 ints
    int* gt  = hdr + 32;                          // B*M ints

    build_idx_kernel<<<B, T1, 0, stream>>>(mask, hdr, gt, M);

    const unsigned long long total = (unsigned long long)out_size;
    const unsigned long long nquads = (total + 3) >> 2;
    const unsigned long long per_block = 256ULL * KQ;
    const unsigned long long blocks = (nquads + per_block - 1) / per_block;
    gather4x4_kernel<<<(unsigned int)blocks, 256, 0, stream>>>(
        x, hdr, gt, out, N, M, cshift, total, magic, rshift);
}